// Round 4
// baseline (4250.841 us; speedup 1.0000x reference)
//
#include <hip/hip_runtime.h>
#include <hip/hip_bf16.h>
#include <stdint.h>

#define H 2048
#define FOURH 8192
#define NT 768
#define NS 256

typedef __attribute__((ext_vector_type(8))) short bf16x8;
typedef __attribute__((ext_vector_type(4))) float f32x4;
typedef __attribute__((ext_vector_type(4))) unsigned uint4v;
typedef unsigned long long u64;

static __device__ __forceinline__ unsigned short f2bf(float x) {
  unsigned u = __float_as_uint(x);
  return (unsigned short)((u + 0x7fffu + ((u >> 16) & 1u)) >> 16);
}
static __device__ __forceinline__ unsigned pk2(float lo, float hi) {
  return ((unsigned)f2bf(hi) << 16) | (unsigned)f2bf(lo);
}
static __device__ __forceinline__ float bflo(unsigned u) { return __uint_as_float(u << 16); }
static __device__ __forceinline__ float bfhi(unsigned u) { return __uint_as_float(u & 0xffff0000u); }
static __device__ __forceinline__ float sigm(float x) { return 1.f / (1.f + __expf(-x)); }
static __device__ __forceinline__ float tanh_fast(float x) {
  float xc = fminf(fmaxf(x, -15.f), 15.f);
  float e = __expf(2.f * xc);
  return (e - 1.f) / (e + 1.f);
}

// ---------------- gather: build X_bf16[768][2048] ----------------
__global__ void gather_x(const int* __restrict__ ctx, const int* __restrict__ f1,
                         const int* __restrict__ f2, const float* __restrict__ ctx_table,
                         const float* __restrict__ face_table, unsigned short* __restrict__ X) {
  int t = blockIdx.x;            // 0..767
  int s = t / 3, k = t - 3 * s;  // sample, sub-step
  const float* src;
  if (k == 0)      src = ctx_table  + (size_t)ctx[s] * H;
  else if (k == 1) src = face_table + (size_t)f1[s] * H;
  else             src = face_table + (size_t)f2[s] * H;
  int c = threadIdx.x * 8;
  float4 v0 = *(const float4*)(src + c);
  float4 v1 = *(const float4*)(src + c + 4);
  uint4 o;
  o.x = pk2(v0.x, v0.y); o.y = pk2(v0.z, v0.w);
  o.z = pk2(v1.x, v1.y); o.w = pk2(v1.z, v1.w);
  *(uint4*)(X + (size_t)t * H + c) = o;
}

// ---------------- GEMM: P[768][8192] = X @ W_ih^T + (b_ih + b_hh) ----------------
__launch_bounds__(256)
__global__ void gemm_p(const unsigned short* __restrict__ X, const float* __restrict__ Wih,
                       const float* __restrict__ bih, const float* __restrict__ bhh,
                       float* __restrict__ P) {
  __shared__ unsigned short Alds[128 * 32];
  __shared__ unsigned short Blds[128 * 32];
  int tid = threadIdx.x;
  int bm = (blockIdx.x >> 6) * 128;   // 6 M-tiles
  int bn = (blockIdx.x & 63) * 128;   // 64 N-tiles
  int w = tid >> 6, l = tid & 63;
  int wm = (w >> 1) * 64, wn = (w & 1) * 64;
  int sr = tid >> 1;             // staging row 0..127
  int sc = (tid & 1) * 16;       // staging col 0 / 16
  int cl = l & 15, kg = (l >> 4) * 8;

  f32x4 acc[4][4];
#pragma unroll
  for (int i = 0; i < 4; ++i)
#pragma unroll
    for (int j = 0; j < 4; ++j) acc[i][j] = (f32x4){0.f, 0.f, 0.f, 0.f};

  for (int kt = 0; kt < H; kt += 32) {
    __syncthreads();
    const unsigned short* ap = X + (size_t)(bm + sr) * H + kt + sc;
    uint4 a0 = *(const uint4*)ap;
    uint4 a1 = *(const uint4*)(ap + 8);
    const float* bp = Wih + (size_t)(bn + sr) * H + kt + sc;
    float4 f0 = *(const float4*)bp;
    float4 f1v = *(const float4*)(bp + 4);
    float4 f2v = *(const float4*)(bp + 8);
    float4 f3v = *(const float4*)(bp + 12);
    *(uint4*)(Alds + sr * 32 + sc) = a0;
    *(uint4*)(Alds + sr * 32 + sc + 8) = a1;
    uint4 b0, b1;
    b0.x = pk2(f0.x, f0.y);  b0.y = pk2(f0.z, f0.w);
    b0.z = pk2(f1v.x, f1v.y); b0.w = pk2(f1v.z, f1v.w);
    b1.x = pk2(f2v.x, f2v.y); b1.y = pk2(f2v.z, f2v.w);
    b1.z = pk2(f3v.x, f3v.y); b1.w = pk2(f3v.z, f3v.w);
    *(uint4*)(Blds + sr * 32 + sc) = b0;
    *(uint4*)(Blds + sr * 32 + sc + 8) = b1;
    __syncthreads();

    bf16x8 af[4], bb[4];
#pragma unroll
    for (int i = 0; i < 4; ++i) {
      af[i] = *(bf16x8*)(Alds + (wm + i * 16 + cl) * 32 + kg);
      bb[i] = *(bf16x8*)(Blds + (wn + i * 16 + cl) * 32 + kg);
    }
#pragma unroll
    for (int i = 0; i < 4; ++i)
#pragma unroll
      for (int j = 0; j < 4; ++j)
        acc[i][j] = __builtin_amdgcn_mfma_f32_16x16x32_bf16(af[i], bb[j], acc[i][j], 0, 0, 0);
  }

  int rg = (l >> 4) * 4;
#pragma unroll
  for (int j = 0; j < 4; ++j) {
    int n = bn + wn + j * 16 + cl;
    float bias = bih[n] + bhh[n];
#pragma unroll
    for (int i = 0; i < 4; ++i) {
      int m = bm + wm + i * 16 + rg;
#pragma unroll
      for (int r = 0; r < 4; ++r)
        P[(size_t)(m + r) * FOURH + n] = acc[i][j][r] + bias;
    }
  }
}

// ---------------- persistent sequential LSTM ----------------
// 256 WGs x 256 threads, 1 WG/CU. WG g owns h rows [g*8, g*8+8).
// Wave G owns 2 complete cells: rows g*8+2G, g*8+2G+1 (all 4 gates) -> after
// the butterfly each wave finishes its cells with NO cross-wave exchange.
// Broadcast: hbuf[2][2048] u32 = (tag16<<16 | bf16(h)); per-dword atomicity is
// all the protocol needs, so polls use coherent dwordx4 loads (sc0 sc1) --
// 2 transactions per thread per round instead of 8 atomic dwords.
// h_lds double-buffered on t&1: single barrier per step bounds wave skew to <1
// step, and skewed waves write the other parity buffer.
__launch_bounds__(256, 1)
__global__ void lstm_seq(const float* __restrict__ Whh, const float* __restrict__ P,
                         unsigned* __restrict__ hbuf, float* __restrict__ hs,
                         float* __restrict__ out) {
  __shared__ float h_lds[2][H];
  int g = blockIdx.x;
  int tid = threadIdx.x;
  int G = tid >> 6, l = tid & 63;

  // weights: q = gate*2 + rowbit; row = g*8 + 2G + rowbit; cols j*256 + l*4
  unsigned wpk[8][8][2];
#pragma unroll
  for (int q = 0; q < 8; ++q) {
    const float* wrow = Whh + ((size_t)(q >> 1) * H + g * 8 + 2 * G + (q & 1)) * H;
#pragma unroll
    for (int j = 0; j < 8; ++j) {
      float4 wv = *(const float4*)(wrow + j * 256 + l * 4);
      wpk[q][j][0] = pk2(wv.x, wv.y);
      wpk[q][j][1] = pk2(wv.z, wv.w);
    }
  }

  float c_state = 0.f;  // every lane redundantly tracks row (l&1); lanes 0,1 store

  for (int t = 0; t < NT; ++t) {
    // P prefetch: lanes 0..7: gate l>>1, rowbit l&1 (issued before the poll)
    float p_v = 0.f;
    if (l < 8)
      p_v = P[(size_t)t * FOURH + (size_t)(l >> 1) * H + g * 8 + 2 * G + (l & 1)];

    // poll own 32B slice of parity buffer with two coherent dwordx4 loads
    uint4v a, b;
    {
      const unsigned* src = hbuf + (size_t)(t & 1) * H + tid * 8;
      unsigned wtag = ((unsigned)t & 0xffffu) << 16;
      for (;;) {
        asm volatile(
            "global_load_dwordx4 %0, %2, off sc0 sc1\n\t"
            "global_load_dwordx4 %1, %3, off sc0 sc1\n\t"
            "s_waitcnt vmcnt(0)"
            : "=&v"(a), "=&v"(b)
            : "v"(src), "v"(src + 4)
            : "memory");
        unsigned m = ((a.x ^ wtag) | (a.y ^ wtag) | (a.z ^ wtag) | (a.w ^ wtag) |
                      (b.x ^ wtag) | (b.y ^ wtag) | (b.z ^ wtag) | (b.w ^ wtag)) &
                     0xffff0000u;
        if (m == 0) break;
        __builtin_amdgcn_s_sleep(1);
      }
      float* hd = &h_lds[t & 1][tid * 8];
      *(float4*)hd = make_float4(__uint_as_float(a.x << 16), __uint_as_float(a.y << 16),
                                 __uint_as_float(a.z << 16), __uint_as_float(a.w << 16));
      *(float4*)(hd + 4) =
          make_float4(__uint_as_float(b.x << 16), __uint_as_float(b.y << 16),
                      __uint_as_float(b.z << 16), __uint_as_float(b.w << 16));
    }
    __syncthreads();

    // matvec: 8 row-gates x 32 cols per thread
    float acc[8] = {0.f, 0.f, 0.f, 0.f, 0.f, 0.f, 0.f, 0.f};
#pragma unroll
    for (int j = 0; j < 8; ++j) {
      float4 hj = *(float4*)&h_lds[t & 1][j * 256 + l * 4];
#pragma unroll
      for (int q = 0; q < 8; ++q) {
        unsigned u0 = wpk[q][j][0], u1 = wpk[q][j][1];
        acc[q] += bflo(u0) * hj.x + bfhi(u0) * hj.y + bflo(u1) * hj.z + bfhi(u1) * hj.w;
      }
    }
    // butterfly reduce over the wave (cols)
#pragma unroll
    for (int q = 0; q < 8; ++q) {
      float v = acc[q];
#pragma unroll
      for (int off = 1; off < 64; off <<= 1) v += __shfl_xor(v, off, 64);
      acc[q] = v;
    }

    // finish both cells redundantly on all lanes (r = l&1); lanes 0,1 store
    int r = l & 1;
    float pi = __shfl(p_v, r, 64);
    float pf = __shfl(p_v, 2 + r, 64);
    float pg = __shfl(p_v, 4 + r, 64);
    float po = __shfl(p_v, 6 + r, 64);
    float ai = r ? acc[1] : acc[0];
    float af = r ? acc[3] : acc[2];
    float ag = r ? acc[5] : acc[4];
    float ao = r ? acc[7] : acc[6];

    float iv = sigm(ai + pi);
    float fv = sigm(af + pf);
    float gv = tanh_fast(ag + pg);
    float ov = sigm(ao + po);
    c_state = fv * c_state + iv * gv;
    float hnew = ov * tanh_fast(c_state);

    if (l < 2) {
      int hidx = g * 8 + 2 * G + l;
      unsigned w = ((((unsigned)(t + 1)) & 0xffffu) << 16) | (unsigned)f2bf(hnew);
      __hip_atomic_store(&hbuf[(size_t)((t + 1) & 1) * H + hidx], w,
                         __ATOMIC_RELAXED, __HIP_MEMORY_SCOPE_AGENT);
      int m3 = t - (t / 3) * 3;
      if (m3 == 2) hs[(size_t)(t / 3) * H + hidx] = hnew;
      if (t == NT - 1) {
        out[512 + hidx] = hnew;        // hF
        out[512 + H + hidx] = c_state; // cF
      }
    }
  }
}

// ---------------- readout: outputs[256][2] ----------------
__global__ void out_head(const float* __restrict__ hs, const float* __restrict__ Wout,
                         const float* __restrict__ bout, float* __restrict__ out) {
  int s = blockIdx.x;
  int l = threadIdx.x;  // 64
  float a0 = 0.f, a1 = 0.f;
#pragma unroll 4
  for (int j = 0; j < 32; ++j) {
    int idx = j * 64 + l;
    float h = hs[(size_t)s * H + idx];
    a0 += h * Wout[idx];
    a1 += h * Wout[H + idx];
  }
#pragma unroll
  for (int off = 1; off < 64; off <<= 1) {
    a0 += __shfl_xor(a0, off, 64);
    a1 += __shfl_xor(a1, off, 64);
  }
  if (l == 0) {
    out[s * 2]     = a0 + bout[0];
    out[s * 2 + 1] = a1 + bout[1];
  }
}

extern "C" void kernel_launch(void* const* d_in, const int* in_sizes, int n_in,
                              void* d_out, int out_size, void* d_ws, size_t ws_size,
                              hipStream_t stream) {
  const int*   ctx        = (const int*)d_in[0];
  const int*   f1         = (const int*)d_in[1];
  const int*   f2         = (const int*)d_in[2];
  const float* ctx_table  = (const float*)d_in[3];
  const float* face_table = (const float*)d_in[4];
  const float* Wih        = (const float*)d_in[5];
  const float* Whh        = (const float*)d_in[6];
  const float* bih        = (const float*)d_in[7];
  const float* bhh        = (const float*)d_in[8];
  const float* Wout       = (const float*)d_in[9];
  const float* bout       = (const float*)d_in[10];
  float* out = (float*)d_out;

  char* ws = (char*)d_ws;
  size_t off = 0;
  unsigned short* X = (unsigned short*)(ws + off); off += (size_t)NT * H * 2;  // 3,145,728
  float* P    = (float*)(ws + off); off += (size_t)NT * FOURH * 4;             // 25,165,824
  unsigned* hbuf = (unsigned*)(ws + off); off += (size_t)2 * H * 4;            // 16,384
  float* hs   = (float*)(ws + off); off += (size_t)NS * H * 4;                 // 2,097,152

  // zero both parity buffers: tag0/value0 for t=0; kills stale tags on replay
  hipMemsetAsync(hbuf, 0, (size_t)2 * H * 4, stream);

  gather_x<<<NT, 256, 0, stream>>>(ctx, f1, f2, ctx_table, face_table, X);
  gemm_p<<<6 * 64, 256, 0, stream>>>(X, Wih, bih, bhh, P);
  lstm_seq<<<NS, 256, 0, stream>>>(Whh, P, hbuf, hs, out);
  out_head<<<NS, 64, 0, stream>>>(hs, Wout, bout, out);
}

// Round 5
// 3323.443 us; speedup vs baseline: 1.2790x; 1.2790x over previous
//
#include <hip/hip_runtime.h>
#include <hip/hip_bf16.h>
#include <stdint.h>

#define H 2048
#define FOURH 8192
#define NT 768
#define NS 256

typedef __attribute__((ext_vector_type(8))) short bf16x8;
typedef __attribute__((ext_vector_type(4))) float f32x4;
typedef __attribute__((ext_vector_type(4))) unsigned uint4v;
typedef unsigned long long u64;

static __device__ __forceinline__ unsigned short f2bf(float x) {
  unsigned u = __float_as_uint(x);
  return (unsigned short)((u + 0x7fffu + ((u >> 16) & 1u)) >> 16);
}
static __device__ __forceinline__ unsigned pk2(float lo, float hi) {
  return ((unsigned)f2bf(hi) << 16) | (unsigned)f2bf(lo);
}
static __device__ __forceinline__ float bflo(unsigned u) { return __uint_as_float(u << 16); }
static __device__ __forceinline__ float bfhi(unsigned u) { return __uint_as_float(u & 0xffff0000u); }
static __device__ __forceinline__ float sigm(float x) { return 1.f / (1.f + __expf(-x)); }
static __device__ __forceinline__ float tanh_fast(float x) {
  float xc = fminf(fmaxf(x, -15.f), 15.f);
  float e = __expf(2.f * xc);
  return (e - 1.f) / (e + 1.f);
}

// ---------------- gather: build X_bf16[768][2048] ----------------
__global__ void gather_x(const int* __restrict__ ctx, const int* __restrict__ f1,
                         const int* __restrict__ f2, const float* __restrict__ ctx_table,
                         const float* __restrict__ face_table, unsigned short* __restrict__ X) {
  int t = blockIdx.x;            // 0..767
  int s = t / 3, k = t - 3 * s;  // sample, sub-step
  const float* src;
  if (k == 0)      src = ctx_table  + (size_t)ctx[s] * H;
  else if (k == 1) src = face_table + (size_t)f1[s] * H;
  else             src = face_table + (size_t)f2[s] * H;
  int c = threadIdx.x * 8;
  float4 v0 = *(const float4*)(src + c);
  float4 v1 = *(const float4*)(src + c + 4);
  uint4 o;
  o.x = pk2(v0.x, v0.y); o.y = pk2(v0.z, v0.w);
  o.z = pk2(v1.x, v1.y); o.w = pk2(v1.z, v1.w);
  *(uint4*)(X + (size_t)t * H + c) = o;
}

// ---------------- GEMM: P[768][8192] = X @ W_ih^T + (b_ih + b_hh) ----------------
__launch_bounds__(256)
__global__ void gemm_p(const unsigned short* __restrict__ X, const float* __restrict__ Wih,
                       const float* __restrict__ bih, const float* __restrict__ bhh,
                       float* __restrict__ P) {
  __shared__ unsigned short Alds[128 * 32];
  __shared__ unsigned short Blds[128 * 32];
  int tid = threadIdx.x;
  int bm = (blockIdx.x >> 6) * 128;   // 6 M-tiles
  int bn = (blockIdx.x & 63) * 128;   // 64 N-tiles
  int w = tid >> 6, l = tid & 63;
  int wm = (w >> 1) * 64, wn = (w & 1) * 64;
  int sr = tid >> 1;             // staging row 0..127
  int sc = (tid & 1) * 16;       // staging col 0 / 16
  int cl = l & 15, kg = (l >> 4) * 8;

  f32x4 acc[4][4];
#pragma unroll
  for (int i = 0; i < 4; ++i)
#pragma unroll
    for (int j = 0; j < 4; ++j) acc[i][j] = (f32x4){0.f, 0.f, 0.f, 0.f};

  for (int kt = 0; kt < H; kt += 32) {
    __syncthreads();
    const unsigned short* ap = X + (size_t)(bm + sr) * H + kt + sc;
    uint4 a0 = *(const uint4*)ap;
    uint4 a1 = *(const uint4*)(ap + 8);
    const float* bp = Wih + (size_t)(bn + sr) * H + kt + sc;
    float4 f0 = *(const float4*)bp;
    float4 f1v = *(const float4*)(bp + 4);
    float4 f2v = *(const float4*)(bp + 8);
    float4 f3v = *(const float4*)(bp + 12);
    *(uint4*)(Alds + sr * 32 + sc) = a0;
    *(uint4*)(Alds + sr * 32 + sc + 8) = a1;
    uint4 b0, b1;
    b0.x = pk2(f0.x, f0.y);  b0.y = pk2(f0.z, f0.w);
    b0.z = pk2(f1v.x, f1v.y); b0.w = pk2(f1v.z, f1v.w);
    b1.x = pk2(f2v.x, f2v.y); b1.y = pk2(f2v.z, f2v.w);
    b1.z = pk2(f3v.x, f3v.y); b1.w = pk2(f3v.z, f3v.w);
    *(uint4*)(Blds + sr * 32 + sc) = b0;
    *(uint4*)(Blds + sr * 32 + sc + 8) = b1;
    __syncthreads();

    bf16x8 af[4], bb[4];
#pragma unroll
    for (int i = 0; i < 4; ++i) {
      af[i] = *(bf16x8*)(Alds + (wm + i * 16 + cl) * 32 + kg);
      bb[i] = *(bf16x8*)(Blds + (wn + i * 16 + cl) * 32 + kg);
    }
#pragma unroll
    for (int i = 0; i < 4; ++i)
#pragma unroll
      for (int j = 0; j < 4; ++j)
        acc[i][j] = __builtin_amdgcn_mfma_f32_16x16x32_bf16(af[i], bb[j], acc[i][j], 0, 0, 0);
  }

  int rg = (l >> 4) * 4;
#pragma unroll
  for (int j = 0; j < 4; ++j) {
    int n = bn + wn + j * 16 + cl;
    float bias = bih[n] + bhh[n];
#pragma unroll
    for (int i = 0; i < 4; ++i) {
      int m = bm + wm + i * 16 + rg;
#pragma unroll
      for (int r = 0; r < 4; ++r)
        P[(size_t)(m + r) * FOURH + n] = acc[i][j][r] + bias;
    }
  }
}

// ---------------- persistent sequential LSTM ----------------
// 256 WGs x 256 threads, 1 WG/CU. WG g owns h elements [g*8, g*8+8).
// Wave G owns gate G's 8 rows; lane l owns cols {j*256 + l*4 + 0..3}.
// Weights in VGPRs (128 packed-bf16-pair regs/thread).
// Broadcast: hbuf[2][2048] u32 = (tag16<<16 | bf16(h)), relaxed agent atomics.
// TWO-TIER fan-out: WGs 0..7 ("importers", round-robin -> XCDs 0..7) poll the
// global hbuf (global fan-out per line: ~32 requesters instead of ~1000) and
// re-publish the raw tagged words into hloc[g] with plain write-back stores
// (allocate in their XCD's L2). All other WGs poll hloc[g&7] with sc0-only
// loads (L1-bypass, L2-served). Tag check makes any stale/torn read retry;
// if the XCD mapping assumption is wrong, a consumer falls back to the
// always-correct global agent-scope poll after 8 local rounds.
__launch_bounds__(256, 1)
__global__ void lstm_seq(const float* __restrict__ Whh, const float* __restrict__ P,
                         unsigned* __restrict__ hbuf, unsigned* __restrict__ hloc,
                         float* __restrict__ hs, float* __restrict__ out) {
  __shared__ float h_lds[H];
  __shared__ float gates_lds[2][32];
  int g = blockIdx.x;
  int tid = threadIdx.x;
  int G = tid >> 6, l = tid & 63;

  // one-time weight load: rows G*2048 + g*8 + q, cols j*256 + l*4 + 0..3
  unsigned wpk[8][8][2];
#pragma unroll
  for (int q = 0; q < 8; ++q) {
    const float* wrow = Whh + (size_t)(G * H + g * 8 + q) * H;
#pragma unroll
    for (int j = 0; j < 8; ++j) {
      float4 wv = *(const float4*)(wrow + j * 256 + l * 4);
      wpk[q][j][0] = pk2(wv.x, wv.y);
      wpk[q][j][1] = pk2(wv.z, wv.w);
    }
  }

  float c_state = 0.f;  // valid for tid < 8

  for (int t = 0; t < NT; ++t) {
    // independent P-row fetch first (overlaps the poll); wave 0 only
    float p_v = 0.f;
    if (tid < 32)
      p_v = P[(size_t)t * FOURH + (size_t)(tid >> 3) * H + g * 8 + (tid & 7)];

    // ---- two-tier tagged poll for this thread's 8 h-words ----
    unsigned v[8];
    {
      unsigned want = ((unsigned)t & 0xffffu) << 16;
      const unsigned* srcg = hbuf + (size_t)(t & 1) * H + tid * 8;
      if (g < 8) {
        // importer: poll global, then re-publish into this XCD's replica
        for (;;) {
          bool ok = true;
#pragma unroll
          for (int i = 0; i < 8; ++i)
            v[i] = __hip_atomic_load(srcg + i, __ATOMIC_RELAXED, __HIP_MEMORY_SCOPE_AGENT);
#pragma unroll
          for (int i = 0; i < 8; ++i) ok &= ((v[i] & 0xffff0000u) == want);
          if (ok) break;
          __builtin_amdgcn_s_sleep(2);
        }
        unsigned* ldst = hloc + ((size_t)g * 2 + (t & 1)) * H + tid * 8;
        *(uint4*)ldst = make_uint4(v[0], v[1], v[2], v[3]);
        *(uint4*)(ldst + 4) = make_uint4(v[4], v[5], v[6], v[7]);
      } else {
        // consumer: poll local XCD replica (L2), fallback to global
        const unsigned* lsrc = hloc + ((size_t)(g & 7) * 2 + (t & 1)) * H + tid * 8;
        int rounds = 0;
        for (;;) {
          uint4v a, b;
          asm volatile(
              "global_load_dwordx4 %0, %2, off sc0\n\t"
              "global_load_dwordx4 %1, %3, off sc0\n\t"
              "s_waitcnt vmcnt(0)"
              : "=&v"(a), "=&v"(b)
              : "v"(lsrc), "v"(lsrc + 4)
              : "memory");
          unsigned m = ((a.x ^ want) | (a.y ^ want) | (a.z ^ want) | (a.w ^ want) |
                        (b.x ^ want) | (b.y ^ want) | (b.z ^ want) | (b.w ^ want)) &
                       0xffff0000u;
          if (m == 0) {
            v[0] = a.x; v[1] = a.y; v[2] = a.z; v[3] = a.w;
            v[4] = b.x; v[5] = b.y; v[6] = b.z; v[7] = b.w;
            break;
          }
          if (++rounds >= 8) {  // mapping/semantics fallback: always correct
            bool ok = true;
#pragma unroll
            for (int i = 0; i < 8; ++i)
              v[i] = __hip_atomic_load(srcg + i, __ATOMIC_RELAXED, __HIP_MEMORY_SCOPE_AGENT);
#pragma unroll
            for (int i = 0; i < 8; ++i) ok &= ((v[i] & 0xffff0000u) == want);
            if (ok) break;
          }
          __builtin_amdgcn_s_sleep(1);
        }
      }
      *(float4*)&h_lds[tid * 8] =
          make_float4(__uint_as_float(v[0] << 16), __uint_as_float(v[1] << 16),
                      __uint_as_float(v[2] << 16), __uint_as_float(v[3] << 16));
      *(float4*)&h_lds[tid * 8 + 4] =
          make_float4(__uint_as_float(v[4] << 16), __uint_as_float(v[5] << 16),
                      __uint_as_float(v[6] << 16), __uint_as_float(v[7] << 16));
    }
    __syncthreads();

    // matvec: 8 rows x 32 cols per thread
    float acc[8] = {0.f, 0.f, 0.f, 0.f, 0.f, 0.f, 0.f, 0.f};
#pragma unroll
    for (int j = 0; j < 8; ++j) {
      float4 hj = *(float4*)&h_lds[j * 256 + l * 4];
#pragma unroll
      for (int q = 0; q < 8; ++q) {
        unsigned u0 = wpk[q][j][0], u1 = wpk[q][j][1];
        acc[q] += bflo(u0) * hj.x + bfhi(u0) * hj.y + bflo(u1) * hj.z + bfhi(u1) * hj.w;
      }
    }
    // butterfly reduce over the wave (cols)
#pragma unroll
    for (int q = 0; q < 8; ++q) {
      float v2 = acc[q];
#pragma unroll
      for (int off = 1; off < 64; off <<= 1) v2 += __shfl_xor(v2, off, 64);
      acc[q] = v2;
    }
    if (l == 0) {
#pragma unroll
      for (int q = 0; q < 8; ++q) gates_lds[t & 1][G * 8 + q] = acc[q];
    }

    // wave 0: distribute the 4 gate biases of row (g*8 + tid&7) via shfl
    float pre_i = 0.f, pre_f = 0.f, pre_g = 0.f, pre_o = 0.f;
    if (tid < 64) {
      int q = tid & 7;
      pre_i = __shfl(p_v, q, 64);
      pre_f = __shfl(p_v, 8 + q, 64);
      pre_g = __shfl(p_v, 16 + q, 64);
      pre_o = __shfl(p_v, 24 + q, 64);
    }
    __syncthreads();

    if (tid < 8) {
      int q = tid;
      float iv = sigm(gates_lds[t & 1][q]      + pre_i);
      float fv = sigm(gates_lds[t & 1][8 + q]  + pre_f);
      float gv = tanh_fast(gates_lds[t & 1][16 + q] + pre_g);
      float ov = sigm(gates_lds[t & 1][24 + q] + pre_o);
      c_state = fv * c_state + iv * gv;
      float hnew = ov * tanh_fast(c_state);
      unsigned w = ((((unsigned)(t + 1)) & 0xffffu) << 16) | (unsigned)f2bf(hnew);
      __hip_atomic_store(&hbuf[(size_t)((t + 1) & 1) * H + g * 8 + q], w,
                         __ATOMIC_RELAXED, __HIP_MEMORY_SCOPE_AGENT);
      int m3 = t - (t / 3) * 3;
      if (m3 == 2) hs[(size_t)(t / 3) * H + g * 8 + q] = hnew;
      if (t == NT - 1) {
        out[512 + g * 8 + q] = hnew;        // hF
        out[512 + H + g * 8 + q] = c_state; // cF
      }
    }
  }
}

// ---------------- readout: outputs[256][2] ----------------
__global__ void out_head(const float* __restrict__ hs, const float* __restrict__ Wout,
                         const float* __restrict__ bout, float* __restrict__ out) {
  int s = blockIdx.x;
  int l = threadIdx.x;  // 64
  float a0 = 0.f, a1 = 0.f;
#pragma unroll 4
  for (int j = 0; j < 32; ++j) {
    int idx = j * 64 + l;
    float h = hs[(size_t)s * H + idx];
    a0 += h * Wout[idx];
    a1 += h * Wout[H + idx];
  }
#pragma unroll
  for (int off = 1; off < 64; off <<= 1) {
    a0 += __shfl_xor(a0, off, 64);
    a1 += __shfl_xor(a1, off, 64);
  }
  if (l == 0) {
    out[s * 2]     = a0 + bout[0];
    out[s * 2 + 1] = a1 + bout[1];
  }
}

extern "C" void kernel_launch(void* const* d_in, const int* in_sizes, int n_in,
                              void* d_out, int out_size, void* d_ws, size_t ws_size,
                              hipStream_t stream) {
  const int*   ctx        = (const int*)d_in[0];
  const int*   f1         = (const int*)d_in[1];
  const int*   f2         = (const int*)d_in[2];
  const float* ctx_table  = (const float*)d_in[3];
  const float* face_table = (const float*)d_in[4];
  const float* Wih        = (const float*)d_in[5];
  const float* Whh        = (const float*)d_in[6];
  const float* bih        = (const float*)d_in[7];
  const float* bhh        = (const float*)d_in[8];
  const float* Wout       = (const float*)d_in[9];
  const float* bout       = (const float*)d_in[10];
  float* out = (float*)d_out;

  char* ws = (char*)d_ws;
  size_t off = 0;
  unsigned short* X = (unsigned short*)(ws + off); off += (size_t)NT * H * 2;  // 3,145,728
  float* P    = (float*)(ws + off); off += (size_t)NT * FOURH * 4;             // 25,165,824
  unsigned* hbuf = (unsigned*)(ws + off); off += (size_t)2 * H * 4;            // 16,384
  unsigned* hloc = (unsigned*)(ws + off); off += (size_t)8 * 2 * H * 4;        // 131,072
  float* hs   = (float*)(ws + off); off += (size_t)NS * H * 4;                 // 2,097,152

  // zero tags: parity-0 tag0/value0 is valid t=0 data; kills stale tags on replay
  hipMemsetAsync(hbuf, 0, (size_t)2 * H * 4, stream);
  hipMemsetAsync(hloc, 0, (size_t)8 * 2 * H * 4, stream);

  gather_x<<<NT, 256, 0, stream>>>(ctx, f1, f2, ctx_table, face_table, X);
  gemm_p<<<6 * 64, 256, 0, stream>>>(X, Wih, bih, bhh, P);
  lstm_seq<<<NS, 256, 0, stream>>>(Whh, P, hbuf, hloc, hs, out);
  out_head<<<NS, 64, 0, stream>>>(hs, Wout, bout, out);
}